// Round 1
// baseline (1610.317 us; speedup 1.0000x reference)
//
#include <hip/hip_runtime.h>
#include <math.h>

namespace {
constexpr int kB = 8, kNG = 5, kNL = 75, kNF = 196, kC = 640;
constexpr int kNTokL = kNL * kNF;      // 14700
constexpr int kNTot = kNG + kNTokL;    // 14705
constexpr float kEps = 1e-12f;
constexpr float kInvAlpha = 10.0f;     // 1 / attention_temperature
}

// s_g[b,c] = sum_g global_f[b,g,c]
__global__ void k_sum_global(const float* __restrict__ gf, float* __restrict__ s_g) {
  const int b = blockIdx.x, c = threadIdx.x;  // block = 640 threads
  float acc = 0.f;
#pragma unroll
  for (int g = 0; g < kNG; ++g) acc += gf[(b * kNG + g) * kC + c];
  s_g[b * kC + c] = acc;
}

// s_l[b,c] = sum_t local_f[b,t,c]  (t = 14700 tokens, sliced over 32 blocks + atomics)
__global__ void k_sum_local(const float* __restrict__ lf, float* __restrict__ s_l) {
  const int b = blockIdx.x, s = blockIdx.y, c = threadIdx.x;  // block = 640 threads
  const int t0 = s * 460, t1 = min(t0 + 460, kNTokL);
  const float* p = lf + ((size_t)b * kNTokL) * kC + c;
  float acc = 0.f;
  for (int t = t0; t < t1; ++t) acc += p[(size_t)t * kC];
  atomicAdd(&s_l[b * kC + c], acc);
}

// One wave per (b,d): m[b,d] = (Wq[d]·s_g[b] + Wk[d]·s_l[b]) / 14705
// gc[b,g,d] = Wq[d]·global_f[b,g] - m[b,d]   (centered global projection)
__global__ void k_proj_mean(const float* __restrict__ Wq, const float* __restrict__ Wk,
                            const float* __restrict__ gf, const float* __restrict__ s_g,
                            const float* __restrict__ s_l, float* __restrict__ m,
                            float* __restrict__ gc) {
  const int wid = blockIdx.x * 4 + (threadIdx.x >> 6);
  const int lane = threadIdx.x & 63;
  const int b = wid / kC, d = wid % kC;
  float aq = 0.f, ak = 0.f, ag[kNG] = {0.f, 0.f, 0.f, 0.f, 0.f};
  for (int c = lane; c < kC; c += 64) {
    const float wq = Wq[d * kC + c];
    const float wk = Wk[d * kC + c];
    aq += wq * s_g[b * kC + c];
    ak += wk * s_l[b * kC + c];
#pragma unroll
    for (int g = 0; g < kNG; ++g) ag[g] += wq * gf[(b * kNG + g) * kC + c];
  }
#pragma unroll
  for (int off = 32; off > 0; off >>= 1) {
    aq += __shfl_xor(aq, off);
    ak += __shfl_xor(ak, off);
#pragma unroll
    for (int g = 0; g < kNG; ++g) ag[g] += __shfl_xor(ag[g], off);
  }
  if (lane == 0) {
    const float mv = (aq + ak) / (float)kNTot;
    m[b * kC + d] = mv;
#pragma unroll
    for (int g = 0; g < kNG; ++g) gc[(b * kNG + g) * kC + d] = ag[g] - mv;
  }
}

// gn = gc / sqrt(||gc||^2 + eps), one block per (b,g) row
__global__ void k_norm_g(const float* __restrict__ gc, float* __restrict__ gn) {
  const int row = blockIdx.x;
  __shared__ float red[256];
  float a = 0.f;
  for (int d = threadIdx.x; d < kC; d += 256) {
    const float v = gc[row * kC + d];
    a += v * v;
  }
  red[threadIdx.x] = a;
  __syncthreads();
  for (int s = 128; s > 0; s >>= 1) {
    if (threadIdx.x < s) red[threadIdx.x] += red[threadIdx.x + s];
    __syncthreads();
  }
  const float rs = 1.0f / sqrtf(red[0] + kEps);
  for (int d = threadIdx.x; d < kC; d += 256) gn[row * kC + d] = gc[row * kC + d] * rs;
}

// The big fused kernel: Y[tile 128 tok x 128 d] = X @ Wk^T chunk, epilogue reduces
// yc = y - m; accumulate ||yc||^2 and yc·gn_g (g=0..4) into global buffers via atomics.
// grid = (5 d-chunks, 115 token tiles, 8 batches), block = 256.
__global__ __launch_bounds__(256) void k_big(
    const float* __restrict__ lf, const float* __restrict__ Wk,
    const float* __restrict__ m, const float* __restrict__ gn,
    float* __restrict__ nsq, float* __restrict__ dots) {
  __shared__ float smem[8192];  // Xs[32][128] | Ws[32][128]
  float* Xs = smem;
  float* Ws = smem + 4096;
  const int tid = threadIdx.x;
  const int tg = tid & 15;   // token group (8 tokens each)
  const int dg = tid >> 4;   // d group (8 d's each)
  const int dchunk = blockIdx.x, tile = blockIdx.y, b = blockIdx.z;
  const int dbase = dchunk * 128;
  const int valid = min(128, kNTokL - tile * 128);
  const size_t xbase = ((size_t)b * kNTokL + (size_t)tile * 128) * kC;

  float acc[8][8];
#pragma unroll
  for (int i = 0; i < 8; ++i)
#pragma unroll
    for (int j = 0; j < 8; ++j) acc[i][j] = 0.f;

  const int lrow = tid >> 1;          // 0..127
  const int lkh = (tid & 1) * 16;     // k half within 32-chunk

  for (int kc = 0; kc < kC; kc += 32) {
    {  // stage X transposed: Xs[k][row]
      float4 v[4] = {};
      if (lrow < valid) {
        const float* p = lf + xbase + (size_t)lrow * kC + kc + lkh;
#pragma unroll
        for (int q = 0; q < 4; ++q) v[q] = *(const float4*)(p + q * 4);
      }
#pragma unroll
      for (int q = 0; q < 4; ++q) {
        Xs[(lkh + q * 4 + 0) * 128 + lrow] = v[q].x;
        Xs[(lkh + q * 4 + 1) * 128 + lrow] = v[q].y;
        Xs[(lkh + q * 4 + 2) * 128 + lrow] = v[q].z;
        Xs[(lkh + q * 4 + 3) * 128 + lrow] = v[q].w;
      }
    }
    {  // stage Wk rows [dbase..dbase+127] transposed: Ws[k][d]
      const float* p = Wk + (size_t)(dbase + lrow) * kC + kc + lkh;
      float4 v[4];
#pragma unroll
      for (int q = 0; q < 4; ++q) v[q] = *(const float4*)(p + q * 4);
#pragma unroll
      for (int q = 0; q < 4; ++q) {
        Ws[(lkh + q * 4 + 0) * 128 + lrow] = v[q].x;
        Ws[(lkh + q * 4 + 1) * 128 + lrow] = v[q].y;
        Ws[(lkh + q * 4 + 2) * 128 + lrow] = v[q].z;
        Ws[(lkh + q * 4 + 3) * 128 + lrow] = v[q].w;
      }
    }
    __syncthreads();
#pragma unroll 4
    for (int k = 0; k < 32; ++k) {
      const float4 x0 = *(const float4*)&Xs[k * 128 + tg * 8];
      const float4 x1 = *(const float4*)&Xs[k * 128 + tg * 8 + 4];
      const float4 w0 = *(const float4*)&Ws[k * 128 + dg * 8];
      const float4 w1 = *(const float4*)&Ws[k * 128 + dg * 8 + 4];
      const float xv[8] = {x0.x, x0.y, x0.z, x0.w, x1.x, x1.y, x1.z, x1.w};
      const float wv[8] = {w0.x, w0.y, w0.z, w0.w, w1.x, w1.y, w1.z, w1.w};
#pragma unroll
      for (int i = 0; i < 8; ++i)
#pragma unroll
        for (int j = 0; j < 8; ++j) acc[i][j] += xv[i] * wv[j];
    }
    __syncthreads();
  }

  // epilogue: center, partial norms + dots for this d-chunk
  float mv[8], gv[5][8];
#pragma unroll
  for (int j = 0; j < 8; ++j) mv[j] = m[b * kC + dbase + dg * 8 + j];
#pragma unroll
  for (int g = 0; g < 5; ++g)
#pragma unroll
    for (int j = 0; j < 8; ++j) gv[g][j] = gn[(b * kNG + g) * kC + dbase + dg * 8 + j];

  const int wv_id = tid >> 6;
#pragma unroll
  for (int i = 0; i < 8; ++i) {
    float part[6] = {0.f, 0.f, 0.f, 0.f, 0.f, 0.f};
#pragma unroll
    for (int j = 0; j < 8; ++j) {
      const float yc = acc[i][j] - mv[j];
      part[0] += yc * yc;
#pragma unroll
      for (int g = 0; g < 5; ++g) part[1 + g] += yc * gv[g][j];
    }
    // reduce over the 4 dg-subgroups within this wave (lanes differ by 16/32)
#pragma unroll
    for (int v = 0; v < 6; ++v) {
      part[v] += __shfl_xor(part[v], 16);
      part[v] += __shfl_xor(part[v], 32);
    }
    if ((tid & 63) < 16) {
#pragma unroll
      for (int v = 0; v < 6; ++v) smem[((wv_id * 16 + tg) * 8 + i) * 6 + v] = part[v];
    }
  }
  __syncthreads();
  // cross-wave reduce (4 waves) + global atomic accumulate, one thread per token
  if (tid < 128 && tid < valid) {
    const int tg2 = tid >> 3, i2 = tid & 7;
    float vals[6];
#pragma unroll
    for (int v = 0; v < 6; ++v) {
      float s = 0.f;
#pragma unroll
      for (int w = 0; w < 4; ++w) s += smem[((w * 16 + tg2) * 8 + i2) * 6 + v];
      vals[v] = s;
    }
    const size_t t = (size_t)b * kNTokL + (size_t)tile * 128 + tid;
    atomicAdd(&nsq[t], vals[0]);
#pragma unroll
    for (int g = 0; g < 5; ++g) atomicAdd(&dots[t * 5 + g], vals[1 + g]);
  }
}

// softmax over f (196) per (b,l,g) row; one wave per row
__global__ void k_softmax(const float* __restrict__ nsq, const float* __restrict__ dots,
                          float* __restrict__ out) {
  const int wid = blockIdx.x * 4 + (threadIdx.x >> 6);
  const int lane = threadIdx.x & 63;
  const int b = wid / (kNL * kNG);
  const int rem = wid % (kNL * kNG);
  const int l = rem / kNG, g = rem % kNG;
  float sv[4];
  float mx = -1e30f;
#pragma unroll
  for (int u = 0; u < 4; ++u) {
    const int f = lane + 64 * u;
    if (f < kNF) {
      const size_t t = (size_t)b * kNTokL + (size_t)l * kNF + f;
      sv[u] = dots[t * 5 + g] * (1.0f / sqrtf(nsq[t] + kEps)) * kInvAlpha;
      mx = fmaxf(mx, sv[u]);
    } else {
      sv[u] = 0.f;
    }
  }
#pragma unroll
  for (int off = 32; off > 0; off >>= 1) mx = fmaxf(mx, __shfl_xor(mx, off));
  float se = 0.f;
#pragma unroll
  for (int u = 0; u < 4; ++u) {
    const int f = lane + 64 * u;
    const float e = (f < kNF) ? expf(sv[u] - mx) : 0.f;
    sv[u] = e;
    se += e;
  }
#pragma unroll
  for (int off = 32; off > 0; off >>= 1) se += __shfl_xor(se, off);
  const float inv = 1.0f / se;
#pragma unroll
  for (int u = 0; u < 4; ++u) {
    const int f = lane + 64 * u;
    if (f < kNF) out[((size_t)(b * kNL + l) * kNG + g) * kNF + f] = sv[u] * inv;
  }
}

extern "C" void kernel_launch(void* const* d_in, const int* in_sizes, int n_in,
                              void* d_out, int out_size, void* d_ws, size_t ws_size,
                              hipStream_t stream) {
  (void)in_sizes; (void)n_in; (void)out_size; (void)ws_size;
  const float* gf = (const float*)d_in[0];  // [8,5,640]
  const float* lf = (const float*)d_in[1];  // [8,75,196,640]
  const float* Wq = (const float*)d_in[2];  // [640,640]
  const float* Wk = (const float*)d_in[3];  // [640,640]
  float* ws = (float*)d_ws;
  // workspace layout (floats)
  float* s_g  = ws;            // 5120
  float* s_l  = ws + 5120;     // 5120
  float* m    = ws + 10240;    // 5120
  float* gc   = ws + 15360;    // 25600
  float* gn   = ws + 40960;    // 25600
  float* nsq  = ws + 66560;    // 117600
  float* dots = ws + 184160;   // 588000
  float* out  = (float*)d_out;

  hipMemsetAsync(s_l, 0, (size_t)5120 * 4, stream);
  hipMemsetAsync(nsq, 0, (size_t)(117600 + 588000) * 4, stream);  // nsq+dots contiguous

  k_sum_global<<<kB, kC, 0, stream>>>(gf, s_g);
  k_sum_local<<<dim3(kB, 32), kC, 0, stream>>>(lf, s_l);
  k_proj_mean<<<(kB * kC) / 4, 256, 0, stream>>>(Wq, Wk, gf, s_g, s_l, m, gc);
  k_norm_g<<<kB * kNG, 256, 0, stream>>>(gc, gn);
  k_big<<<dim3(5, 115, kB), 256, 0, stream>>>(lf, Wk, m, gn, nsq, dots);
  k_softmax<<<750, 256, 0, stream>>>(nsq, dots, out);
}

// Round 2
// 946.675 us; speedup vs baseline: 1.7010x; 1.7010x over previous
//
#include <hip/hip_runtime.h>
#include <math.h>

namespace {
constexpr int kB = 8, kNG = 5, kNL = 75, kNF = 196, kC = 640;
constexpr int kNTokL = kNL * kNF;      // 14700
constexpr int kNTot = kNG + kNTokL;    // 14705
constexpr float kEps = 1e-12f;
constexpr float kInvAlpha = 10.0f;     // 1 / attention_temperature
}

typedef __attribute__((ext_vector_type(8))) short short8;
typedef __attribute__((ext_vector_type(4))) float floatx4;

union S8U { short8 v; ushort u[8]; };

// round-to-nearest-even bf16 split: x ~= hi + lo
__device__ __forceinline__ void bsplit(float x, ushort& h, ushort& l) {
  union { float f; uint u; } a; a.f = x;
  uint uh = (a.u + 0x7FFFu + ((a.u >> 16) & 1u)) >> 16;
  h = (ushort)uh;
  union { uint u; float f; } bb; bb.u = uh << 16;
  float r = x - bb.f;
  union { float f; uint u; } c; c.f = r;
  l = (ushort)((c.u + 0x7FFFu + ((c.u >> 16) & 1u)) >> 16);
}

// ---------- small kernels ----------

// s_l[b,c] = sum_t local_f[b,t,c]
__global__ void k_sum_local(const float* __restrict__ lf, float* __restrict__ s_l) {
  const int b = blockIdx.x, s = blockIdx.y, c = threadIdx.x;  // block = 640 threads
  const int t0 = s * 460, t1 = min(t0 + 460, kNTokL);
  const float* p = lf + ((size_t)b * kNTokL) * kC + c;
  float acc = 0.f;
  for (int t = t0; t < t1; ++t) acc += p[(size_t)t * kC];
  atomicAdd(&s_l[b * kC + c], acc);
}

// split Wk into bf16 hi/lo
__global__ void k_cvtW(const float* __restrict__ Wk, ushort* __restrict__ Wh,
                       ushort* __restrict__ Wl) {
  const int i = blockIdx.x * 256 + threadIdx.x;  // 0 .. 409599
  ushort h, l;
  bsplit(Wk[i], h, l);
  Wh[i] = h; Wl[i] = l;
}

// One wave per (b,d): m[b,d] = (Wq[d]·sum_g gf + Wk[d]·s_l[b]) / 14705
// gc[b,g,d] = Wq[d]·gf[b,g] - m[b,d]
__global__ void k_proj_mean(const float* __restrict__ Wq, const float* __restrict__ Wk,
                            const float* __restrict__ gf, const float* __restrict__ s_l,
                            float* __restrict__ m, float* __restrict__ gc) {
  const int wid = blockIdx.x * 4 + (threadIdx.x >> 6);
  const int lane = threadIdx.x & 63;
  const int b = wid / kC, d = wid % kC;
  float ak = 0.f, ag[kNG] = {0.f, 0.f, 0.f, 0.f, 0.f};
  for (int c = lane; c < kC; c += 64) {
    const float wq = Wq[d * kC + c];
    const float wk = Wk[d * kC + c];
    ak += wk * s_l[b * kC + c];
#pragma unroll
    for (int g = 0; g < kNG; ++g) ag[g] += wq * gf[(b * kNG + g) * kC + c];
  }
#pragma unroll
  for (int off = 32; off > 0; off >>= 1) {
    ak += __shfl_xor(ak, off);
#pragma unroll
    for (int g = 0; g < kNG; ++g) ag[g] += __shfl_xor(ag[g], off);
  }
  if (lane == 0) {
    float aq = 0.f;
#pragma unroll
    for (int g = 0; g < kNG; ++g) aq += ag[g];
    const float mv = (aq + ak) / (float)kNTot;
    m[b * kC + d] = mv;
#pragma unroll
    for (int g = 0; g < kNG; ++g) gc[(b * kNG + g) * kC + d] = ag[g] - mv;
  }
}

// gn = gc / sqrt(||gc||^2 + eps), one block per (b,g) row
__global__ void k_norm_g(const float* __restrict__ gc, float* __restrict__ gn) {
  const int row = blockIdx.x;
  __shared__ float red[256];
  float a = 0.f;
  for (int d = threadIdx.x; d < kC; d += 256) {
    const float v = gc[row * kC + d];
    a += v * v;
  }
  red[threadIdx.x] = a;
  __syncthreads();
  for (int s = 128; s > 0; s >>= 1) {
    if (threadIdx.x < s) red[threadIdx.x] += red[threadIdx.x + s];
    __syncthreads();
  }
  const float rs = 1.0f / sqrtf(red[0] + kEps);
  for (int d = threadIdx.x; d < kC; d += 256) gn[row * kC + d] = gc[row * kC + d] * rs;
}

// ---------- the big MFMA kernel ----------
// Y[128 tok x 128 d] = X @ Wk^T via bf16-split (3 MFMA per frag pair).
// Epilogue: yc = y - m; atomically accumulate ||yc||^2 and yc·gn_g.
// grid = (5 d-chunks, 115 token tiles, 8 batches), block = 256 (4 waves).
#define LDSTR 40  // padded row stride in bf16 elems (80B; bank stride 20 -> 2-way, free)
__global__ __launch_bounds__(256, 2) void k_big(
    const float* __restrict__ lf, const ushort* __restrict__ Wh,
    const ushort* __restrict__ Wl, const float* __restrict__ m,
    const float* __restrict__ gn, float* __restrict__ nsq, float* __restrict__ dots) {
  __shared__ ushort Ah[128 * LDSTR];
  __shared__ ushort Al[128 * LDSTR];
  __shared__ ushort Bh[128 * LDSTR];
  __shared__ ushort Bl[128 * LDSTR];

  const int tid = threadIdx.x;
  const int dchunk = blockIdx.x, tile = blockIdx.y, b = blockIdx.z;
  const int dbase = dchunk * 128;
  const int valid = min(128, kNTokL - tile * 128);
  const size_t xbase = ((size_t)b * kNTokL + (size_t)tile * 128) * kC;

  const int wid = tid >> 6, lane = tid & 63;
  const int wm = wid >> 1, wn = wid & 1;      // wave tile position (2x2 of 64x64)
  const int fm = lane & 15;                   // row/col within 16-tile
  const int kq = (lane >> 4) * 8;             // k offset of this quad

  floatx4 acc[4][4];
#pragma unroll
  for (int i = 0; i < 4; ++i)
#pragma unroll
    for (int j = 0; j < 4; ++j) acc[i][j] = (floatx4){0.f, 0.f, 0.f, 0.f};

  const int r = tid >> 1;            // staging row 0..127
  const int kh = (tid & 1) * 16;     // k half

  for (int kc = 0; kc < kC; kc += 32) {
    {  // stage A: lf row r, k slice [kc+kh, +16), split to bf16 hi/lo
      float4 f[4] = {};
      if (r < valid) {
        const float* p = lf + xbase + (size_t)r * kC + kc + kh;
#pragma unroll
        for (int q = 0; q < 4; ++q) f[q] = *(const float4*)(p + q * 4);
      }
      S8U h0, h1, l0, l1;
      const float* fs = (const float*)f;
#pragma unroll
      for (int e = 0; e < 8; ++e) bsplit(fs[e], h0.u[e], l0.u[e]);
#pragma unroll
      for (int e = 0; e < 8; ++e) bsplit(fs[8 + e], h1.u[e], l1.u[e]);
      *(short8*)&Ah[r * LDSTR + kh] = h0.v;
      *(short8*)&Ah[r * LDSTR + kh + 8] = h1.v;
      *(short8*)&Al[r * LDSTR + kh] = l0.v;
      *(short8*)&Al[r * LDSTR + kh + 8] = l1.v;
    }
    {  // stage B: Wh/Wl row dbase+r, same k slice (already bf16)
      const ushort* ph = Wh + (size_t)(dbase + r) * kC + kc + kh;
      const ushort* pl = Wl + (size_t)(dbase + r) * kC + kc + kh;
      float4 bh0 = *(const float4*)ph;        // 8 bf16
      float4 bh1 = *(const float4*)(ph + 8);
      float4 bl0 = *(const float4*)pl;
      float4 bl1 = *(const float4*)(pl + 8);
      *(float4*)&Bh[r * LDSTR + kh] = bh0;
      *(float4*)&Bh[r * LDSTR + kh + 8] = bh1;
      *(float4*)&Bl[r * LDSTR + kh] = bl0;
      *(float4*)&Bl[r * LDSTR + kh + 8] = bl1;
    }
    __syncthreads();

    short8 ah[4], al[4], bh[4], bl[4];
#pragma unroll
    for (int t = 0; t < 4; ++t) {
      ah[t] = *(const short8*)&Ah[(wm * 64 + t * 16 + fm) * LDSTR + kq];
      al[t] = *(const short8*)&Al[(wm * 64 + t * 16 + fm) * LDSTR + kq];
      bh[t] = *(const short8*)&Bh[(wn * 64 + t * 16 + fm) * LDSTR + kq];
      bl[t] = *(const short8*)&Bl[(wn * 64 + t * 16 + fm) * LDSTR + kq];
    }
#pragma unroll
    for (int mt = 0; mt < 4; ++mt)
#pragma unroll
      for (int nt = 0; nt < 4; ++nt) {
        acc[mt][nt] = __builtin_amdgcn_mfma_f32_16x16x32_bf16(ah[mt], bh[nt], acc[mt][nt], 0, 0, 0);
        acc[mt][nt] = __builtin_amdgcn_mfma_f32_16x16x32_bf16(al[mt], bh[nt], acc[mt][nt], 0, 0, 0);
        acc[mt][nt] = __builtin_amdgcn_mfma_f32_16x16x32_bf16(ah[mt], bl[nt], acc[mt][nt], 0, 0, 0);
      }
    __syncthreads();
  }

  // ---- epilogue: center, reduce over d, atomic accumulate per token ----
  float mv[4], gv[5][4];
#pragma unroll
  for (int nt = 0; nt < 4; ++nt) {
    const int d = dbase + wn * 64 + nt * 16 + fm;
    mv[nt] = m[b * kC + d];
#pragma unroll
    for (int g = 0; g < 5; ++g) gv[g][nt] = gn[(b * kNG + g) * kC + d];
  }

#pragma unroll
  for (int mt = 0; mt < 4; ++mt)
#pragma unroll
    for (int reg = 0; reg < 4; ++reg) {
      float part[6] = {0.f, 0.f, 0.f, 0.f, 0.f, 0.f};
#pragma unroll
      for (int nt = 0; nt < 4; ++nt) {
        const float yc = acc[mt][nt][reg] - mv[nt];
        part[0] += yc * yc;
#pragma unroll
        for (int g = 0; g < 5; ++g) part[1 + g] += yc * gv[g][nt];
      }
      // reduce over the 16 lanes (lane&15) that share this token row
#pragma unroll
      for (int off = 1; off < 16; off <<= 1)
#pragma unroll
        for (int v = 0; v < 6; ++v) part[v] += __shfl_xor(part[v], off);
      const int row128 = wm * 64 + mt * 16 + (lane >> 4) * 4 + reg;
      if (fm == 0 && row128 < valid) {
        const size_t t = (size_t)b * kNTokL + (size_t)tile * 128 + row128;
        atomicAdd(&nsq[t], part[0]);
#pragma unroll
        for (int g = 0; g < 5; ++g)
          atomicAdd(&dots[(size_t)g * (kB * kNTokL) + t], part[1 + g]);
      }
    }
}

// softmax over f (196) per (b,l,g) row; one wave per row
__global__ void k_softmax(const float* __restrict__ nsq, const float* __restrict__ dots,
                          float* __restrict__ out) {
  const int wid = blockIdx.x * 4 + (threadIdx.x >> 6);
  const int lane = threadIdx.x & 63;
  const int b = wid / (kNL * kNG);
  const int rem = wid % (kNL * kNG);
  const int l = rem / kNG, g = rem % kNG;
  float sv[4];
  float mx = -1e30f;
#pragma unroll
  for (int u = 0; u < 4; ++u) {
    const int f = lane + 64 * u;
    if (f < kNF) {
      const size_t t = (size_t)b * kNTokL + (size_t)l * kNF + f;
      sv[u] = dots[(size_t)g * (kB * kNTokL) + t] * (1.0f / sqrtf(nsq[t] + kEps)) * kInvAlpha;
      mx = fmaxf(mx, sv[u]);
    } else {
      sv[u] = 0.f;
    }
  }
#pragma unroll
  for (int off = 32; off > 0; off >>= 1) mx = fmaxf(mx, __shfl_xor(mx, off));
  float se = 0.f;
#pragma unroll
  for (int u = 0; u < 4; ++u) {
    const int f = lane + 64 * u;
    const float e = (f < kNF) ? expf(sv[u] - mx) : 0.f;
    sv[u] = e;
    se += e;
  }
#pragma unroll
  for (int off = 32; off > 0; off >>= 1) se += __shfl_xor(se, off);
  const float inv = 1.0f / se;
#pragma unroll
  for (int u = 0; u < 4; ++u) {
    const int f = lane + 64 * u;
    if (f < kNF) out[((size_t)(b * kNL + l) * kNG + g) * kNF + f] = sv[u] * inv;
  }
}

extern "C" void kernel_launch(void* const* d_in, const int* in_sizes, int n_in,
                              void* d_out, int out_size, void* d_ws, size_t ws_size,
                              hipStream_t stream) {
  (void)in_sizes; (void)n_in; (void)out_size; (void)ws_size;
  const float* gf = (const float*)d_in[0];  // [8,5,640]
  const float* lf = (const float*)d_in[1];  // [8,75,196,640]
  const float* Wq = (const float*)d_in[2];  // [640,640]
  const float* Wk = (const float*)d_in[3];  // [640,640]
  float* ws = (float*)d_ws;
  // workspace layout (float offsets)
  float* s_l  = ws;             // 5120
  float* m    = ws + 5120;      // 5120
  float* gc   = ws + 10240;     // 25600
  float* gn   = ws + 35840;     // 25600
  float* nsq  = ws + 61440;     // 117600
  float* dots = ws + 179040;    // 5*117600 = 588000  (layout [g][t])
  ushort* Wh  = (ushort*)(ws + 767040);           // 409600 ushort = 204800 floats
  ushort* Wl  = (ushort*)(ws + 767040 + 204800);  // 409600 ushort
  float* out  = (float*)d_out;

  hipMemsetAsync(s_l, 0, (size_t)5120 * 4, stream);
  hipMemsetAsync(nsq, 0, (size_t)(117600 + 588000) * 4, stream);  // nsq+dots contiguous

  k_sum_local<<<dim3(kB, 32), kC, 0, stream>>>(lf, s_l);
  k_cvtW<<<1600, 256, 0, stream>>>(Wk, Wh, Wl);
  k_proj_mean<<<(kB * kC) / 4, 256, 0, stream>>>(Wq, Wk, gf, s_l, m, gc);
  k_norm_g<<<kB * kNG, 256, 0, stream>>>(gc, gn);
  k_big<<<dim3(5, 115, kB), 256, 0, stream>>>(lf, Wh, Wl, m, gn, nsq, dots);
  k_softmax<<<750, 256, 0, stream>>>(nsq, dots, out);
}

// Round 3
// 934.646 us; speedup vs baseline: 1.7229x; 1.0129x over previous
//
#include <hip/hip_runtime.h>
#include <math.h>

namespace {
constexpr int kB = 8, kNG = 5, kNL = 75, kNF = 196, kC = 640;
constexpr int kNTokL = kNL * kNF;      // 14700
constexpr int kNTot = kNG + kNTokL;    // 14705
constexpr float kEps = 1e-12f;
constexpr float kInvAlpha = 10.0f;
constexpr int kTilesPerB = 920;        // padded 16-token tiles per batch (14720 tokens)
constexpr int kKC = 20;                // 640 / 32 K-chunks
}

typedef __attribute__((ext_vector_type(8))) short short8;
typedef __attribute__((ext_vector_type(4))) short short4v;
typedef __attribute__((ext_vector_type(4))) float floatx4;

union S8U { short8 v; ushort u[8]; };
union S4U { short4v v; ushort u[4]; };

// round-to-nearest-even bf16 split: x ~= hi + lo
__device__ __forceinline__ void bsplit(float x, ushort& h, ushort& l) {
  union { float f; uint u; } a; a.f = x;
  uint uh = (a.u + 0x7FFFu + ((a.u >> 16) & 1u)) >> 16;
  h = (ushort)uh;
  union { uint u; float f; } bb; bb.u = uh << 16;
  float r = x - bb.f;
  union { float f; uint u; } c; c.f = r;
  l = (ushort)((c.u + 0x7FFFu + ((c.u >> 16) & 1u)) >> 16);
}

#define MFMA_BF16(a, b, c) __builtin_amdgcn_mfma_f32_16x16x32_bf16(a, b, c, 0, 0, 0)

// ===================== shared small kernels =====================

// One wave per (b,d): m[b,d] = (Wq[d]·sum_g gf + Wk[d]·s_l[b]) / 14705
// gc[b,g,d] = Wq[d]·gf[b,g] - m[b,d]
__global__ void k_proj_mean(const float* __restrict__ Wq, const float* __restrict__ Wk,
                            const float* __restrict__ gf, const float* __restrict__ s_l,
                            float* __restrict__ m, float* __restrict__ gc) {
  const int wid = blockIdx.x * 4 + (threadIdx.x >> 6);
  const int lane = threadIdx.x & 63;
  const int b = wid / kC, d = wid % kC;
  float ak = 0.f, ag[kNG] = {0.f, 0.f, 0.f, 0.f, 0.f};
  for (int c = lane; c < kC; c += 64) {
    const float wq = Wq[d * kC + c];
    const float wk = Wk[d * kC + c];
    ak += wk * s_l[b * kC + c];
#pragma unroll
    for (int g = 0; g < kNG; ++g) ag[g] += wq * gf[(b * kNG + g) * kC + c];
  }
#pragma unroll
  for (int off = 32; off > 0; off >>= 1) {
    ak += __shfl_xor(ak, off);
#pragma unroll
    for (int g = 0; g < kNG; ++g) ag[g] += __shfl_xor(ag[g], off);
  }
  if (lane == 0) {
    float aq = 0.f;
#pragma unroll
    for (int g = 0; g < kNG; ++g) aq += ag[g];
    const float mv = (aq + ak) / (float)kNTot;
    m[b * kC + d] = mv;
#pragma unroll
    for (int g = 0; g < kNG; ++g) gc[(b * kNG + g) * kC + d] = ag[g] - mv;
  }
}

__global__ void k_norm_g(const float* __restrict__ gc, float* __restrict__ gn) {
  const int row = blockIdx.x;
  __shared__ float red[256];
  float a = 0.f;
  for (int d = threadIdx.x; d < kC; d += 256) {
    const float v = gc[row * kC + d];
    a += v * v;
  }
  red[threadIdx.x] = a;
  __syncthreads();
  for (int s = 128; s > 0; s >>= 1) {
    if (threadIdx.x < s) red[threadIdx.x] += red[threadIdx.x + s];
    __syncthreads();
  }
  const float rs = 1.0f / sqrtf(red[0] + kEps);
  for (int d = threadIdx.x; d < kC; d += 256) gn[row * kC + d] = gc[row * kC + d] * rs;
}

__global__ void k_softmax(const float* __restrict__ nsq, const float* __restrict__ dots,
                          float* __restrict__ out) {
  const int wid = blockIdx.x * 4 + (threadIdx.x >> 6);
  const int lane = threadIdx.x & 63;
  const int b = wid / (kNL * kNG);
  const int rem = wid % (kNL * kNG);
  const int l = rem / kNG, g = rem % kNG;
  float sv[4];
  float mx = -1e30f;
#pragma unroll
  for (int u = 0; u < 4; ++u) {
    const int f = lane + 64 * u;
    if (f < kNF) {
      const size_t t = (size_t)b * kNTokL + (size_t)l * kNF + f;
      sv[u] = dots[(size_t)g * (kB * kNTokL) + t] * (1.0f / sqrtf(nsq[t] + kEps)) * kInvAlpha;
      mx = fmaxf(mx, sv[u]);
    } else {
      sv[u] = 0.f;
    }
  }
#pragma unroll
  for (int off = 32; off > 0; off >>= 1) mx = fmaxf(mx, __shfl_xor(mx, off));
  float se = 0.f;
#pragma unroll
  for (int u = 0; u < 4; ++u) {
    const int f = lane + 64 * u;
    const float e = (f < kNF) ? expf(sv[u] - mx) : 0.f;
    sv[u] = e;
    se += e;
  }
#pragma unroll
  for (int off = 32; off > 0; off >>= 1) se += __shfl_xor(se, off);
  const float inv = 1.0f / se;
#pragma unroll
  for (int u = 0; u < 4; ++u) {
    const int f = lane + 64 * u;
    if (f < kNF) out[((size_t)(b * kNL + l) * kNG + g) * kNF + f] = sv[u] * inv;
  }
}

// ===================== main path: fragment-precomputed =====================

// prep: read lf once; write Xh/Xl as row-major 16tok x 32k bf16 tiles
// (tile = 1KB: row m -> 32 bf16 = 64B) and accumulate column sums s_l.
// grid = (10, kc=20, b=8), 256 threads = 4 waves.
// wave handles half-tiles h = waveslot + 40*i (i<46); half-tile = 8 tokens x 32 k.
// lane: tokrow = lane>>3 (0..7), k4 = lane&7 (float4 column group).
__global__ void k_prep(const float* __restrict__ lf, ushort* __restrict__ Xh,
                       ushort* __restrict__ Xl, float* __restrict__ s_l) {
  const int tid = threadIdx.x;
  const int wid = tid >> 6, lane = tid & 63;
  const int waveslot = blockIdx.x * 4 + wid;  // 0..39
  const int kc = blockIdx.y, b = blockIdx.z;
  const int mrow = lane >> 3, k4 = lane & 7;

  float sum[4] = {0.f, 0.f, 0.f, 0.f};
  for (int i = 0; i < 46; ++i) {
    const int h = waveslot + 40 * i;        // 0..1839
    const int t = h * 8 + mrow;             // token
    float4 x = {0.f, 0.f, 0.f, 0.f};
    if (t < kNTokL)
      x = *(const float4*)(lf + ((size_t)b * kNTokL + t) * kC + kc * 32 + k4 * 4);
    S4U hh, ll;
    bsplit(x.x, hh.u[0], ll.u[0]);
    bsplit(x.y, hh.u[1], ll.u[1]);
    bsplit(x.z, hh.u[2], ll.u[2]);
    bsplit(x.w, hh.u[3], ll.u[3]);
    const int tt = h >> 1, half = h & 1;
    // tile base (shorts) + within-tile offset: half*256 + mrow*32 + k4*4  (= lane*4 + half*256)
    const size_t off = ((size_t)(b * kTilesPerB + tt) * kKC + kc) * 512 + half * 256 + lane * 4;
    *(short4v*)(Xh + off) = hh.v;
    *(short4v*)(Xl + off) = ll.v;
    sum[0] += x.x; sum[1] += x.y; sum[2] += x.z; sum[3] += x.w;
  }
  // reduce over the 8 token-rows (lanes differing in bits 3..5)
#pragma unroll
  for (int off = 8; off < 64; off <<= 1)
#pragma unroll
    for (int j = 0; j < 4; ++j) sum[j] += __shfl_xor(sum[j], off);
  if (lane < 8) {
#pragma unroll
    for (int j = 0; j < 4; ++j)
      atomicAdd(&s_l[b * kC + kc * 32 + lane * 4 + j], sum[j]);
  }
}

// W prep: Wk -> Wh/Wl in the same row-major 16x32 tile layout.
// 1600 half-tiles (40 dt x 20 kc x 2 halves); one wave each; grid 400 x 256.
__global__ void k_cvtW_frag(const float* __restrict__ Wk, ushort* __restrict__ Wh,
                            ushort* __restrict__ Wl) {
  const int wv = blockIdx.x * 4 + (threadIdx.x >> 6);  // 0..1599
  const int lane = threadIdx.x & 63;
  const int half = wv & 1, kc = (wv >> 1) % kKC, dt = wv / (2 * kKC);
  const int mrow = lane >> 3, k4 = lane & 7;
  const int d = dt * 16 + half * 8 + mrow;
  float4 x = *(const float4*)(Wk + (size_t)d * kC + kc * 32 + k4 * 4);
  S4U hh, ll;
  bsplit(x.x, hh.u[0], ll.u[0]);
  bsplit(x.y, hh.u[1], ll.u[1]);
  bsplit(x.z, hh.u[2], ll.u[2]);
  bsplit(x.w, hh.u[3], ll.u[3]);
  const size_t off = ((size_t)dt * kKC + kc) * 512 + half * 256 + lane * 4;
  *(short4v*)(Wh + off) = hh.v;
  *(short4v*)(Wl + off) = ll.v;
}

// k_big: LDS-free, barrier-free. 1D grid 4600: bid = tile*40 + dchunk*8 + b
// (co-locates the 5 dchunk siblings on one XCD, co-resident in time).
// Block = 4 waves in 2x2; wave = 64 tok x 64 d of the 128x128 tile.
__global__ __launch_bounds__(256, 2) void k_big(
    const ushort* __restrict__ Xh, const ushort* __restrict__ Xl,
    const ushort* __restrict__ Wh, const ushort* __restrict__ Wl,
    const float* __restrict__ m, const float* __restrict__ gn,
    float* __restrict__ nsq, float* __restrict__ dots) {
  const int bid = blockIdx.x;
  const int tile = bid / 40;
  const int r40 = bid % 40;
  const int dchunk = r40 >> 3, b = r40 & 7;
  const int tid = threadIdx.x;
  const int wid = tid >> 6, lane = tid & 63;
  const int wm = wid >> 1, wn = wid & 1;
  const int fm = lane & 15;
  const int valid = min(128, kNTokL - tile * 128);

  // within-tile fragment offset (shorts): row-major 16x32 tile
  const int laneoff = fm * 32 + (lane >> 4) * 8;

  const ushort* pAh = Xh + ((size_t)(b * kTilesPerB + tile * 8 + wm * 4) * kKC) * 512 + laneoff;
  const ushort* pAl = Xl + ((size_t)(b * kTilesPerB + tile * 8 + wm * 4) * kKC) * 512 + laneoff;
  const ushort* pBh = Wh + ((size_t)(dchunk * 8 + wn * 4) * kKC) * 512 + laneoff;
  const ushort* pBl = Wl + ((size_t)(dchunk * 8 + wn * 4) * kKC) * 512 + laneoff;

  floatx4 acc[4][4];
#pragma unroll
  for (int i = 0; i < 4; ++i)
#pragma unroll
    for (int j = 0; j < 4; ++j) acc[i][j] = (floatx4){0.f, 0.f, 0.f, 0.f};

#define LOADF(AH, AL, BH, BL, KCI)                                   \
  {                                                                  \
    const int _o = (KCI) * 512;                                      \
    _Pragma("unroll") for (int t = 0; t < 4; ++t) {                  \
      AH[t] = *(const short8*)(pAh + (size_t)t * (kKC * 512) + _o);  \
      AL[t] = *(const short8*)(pAl + (size_t)t * (kKC * 512) + _o);  \
      BH[t] = *(const short8*)(pBh + (size_t)t * (kKC * 512) + _o);  \
      BL[t] = *(const short8*)(pBl + (size_t)t * (kKC * 512) + _o);  \
    }                                                                \
  }

#define DOMFMA(AH, AL, BH, BL)                                       \
  {                                                                  \
    _Pragma("unroll") for (int mt = 0; mt < 4; ++mt)                 \
        _Pragma("unroll") for (int nt = 0; nt < 4; ++nt) {           \
      acc[mt][nt] = MFMA_BF16(AH[mt], BH[nt], acc[mt][nt]);          \
      acc[mt][nt] = MFMA_BF16(AL[mt], BH[nt], acc[mt][nt]);          \
      acc[mt][nt] = MFMA_BF16(AH[mt], BL[nt], acc[mt][nt]);          \
    }                                                                \
  }

  short8 a0h[4], a0l[4], b0h[4], b0l[4];
  short8 a1h[4], a1l[4], b1h[4], b1l[4];
  LOADF(a0h, a0l, b0h, b0l, 0);
#pragma unroll 2
  for (int kc = 0; kc < kKC; kc += 2) {
    LOADF(a1h, a1l, b1h, b1l, kc + 1);
    DOMFMA(a0h, a0l, b0h, b0l);
    if (kc + 2 < kKC) LOADF(a0h, a0l, b0h, b0l, kc + 2);
    DOMFMA(a1h, a1l, b1h, b1l);
  }

  // ---- epilogue ----
  float mv[4], gv[5][4];
#pragma unroll
  for (int nt = 0; nt < 4; ++nt) {
    const int d = dchunk * 128 + wn * 64 + nt * 16 + fm;
    mv[nt] = m[b * kC + d];
#pragma unroll
    for (int g = 0; g < 5; ++g) gv[g][nt] = gn[(b * kNG + g) * kC + d];
  }

#pragma unroll
  for (int mt = 0; mt < 4; ++mt)
#pragma unroll
    for (int reg = 0; reg < 4; ++reg) {
      float part[6] = {0.f, 0.f, 0.f, 0.f, 0.f, 0.f};
#pragma unroll
      for (int nt = 0; nt < 4; ++nt) {
        const float yc = acc[mt][nt][reg] - mv[nt];
        part[0] += yc * yc;
#pragma unroll
        for (int g = 0; g < 5; ++g) part[1 + g] += yc * gv[g][nt];
      }
#pragma unroll
      for (int off = 1; off < 16; off <<= 1)
#pragma unroll
        for (int v = 0; v < 6; ++v) part[v] += __shfl_xor(part[v], off);
      const int row128 = wm * 64 + mt * 16 + (lane >> 4) * 4 + reg;
      if (fm == 0 && row128 < valid) {
        const size_t t = (size_t)b * kNTokL + (size_t)tile * 128 + row128;
        atomicAdd(&nsq[t], part[0]);
#pragma unroll
        for (int g = 0; g < 5; ++g)
          atomicAdd(&dots[(size_t)g * (kB * kNTokL) + t], part[1 + g]);
      }
    }
#undef LOADF
#undef DOMFMA
}

// ===================== fallback path (R2, small-ws) =====================

__global__ void fb_sum_local(const float* __restrict__ lf, float* __restrict__ s_l) {
  const int b = blockIdx.x, s = blockIdx.y, c = threadIdx.x;
  const int t0 = s * 460, t1 = min(t0 + 460, kNTokL);
  const float* p = lf + ((size_t)b * kNTokL) * kC + c;
  float acc = 0.f;
  for (int t = t0; t < t1; ++t) acc += p[(size_t)t * kC];
  atomicAdd(&s_l[b * kC + c], acc);
}

__global__ void fb_cvtW(const float* __restrict__ Wk, ushort* __restrict__ Wh,
                        ushort* __restrict__ Wl) {
  const int i = blockIdx.x * 256 + threadIdx.x;
  ushort h, l;
  bsplit(Wk[i], h, l);
  Wh[i] = h; Wl[i] = l;
}

#define LDSTR 40
__global__ __launch_bounds__(256, 2) void fb_big(
    const float* __restrict__ lf, const ushort* __restrict__ Wh,
    const ushort* __restrict__ Wl, const float* __restrict__ m,
    const float* __restrict__ gn, float* __restrict__ nsq, float* __restrict__ dots) {
  __shared__ ushort Ah[128 * LDSTR];
  __shared__ ushort Al[128 * LDSTR];
  __shared__ ushort Bh[128 * LDSTR];
  __shared__ ushort Bl[128 * LDSTR];
  const int tid = threadIdx.x;
  const int dchunk = blockIdx.x, tile = blockIdx.y, b = blockIdx.z;
  const int dbase = dchunk * 128;
  const int valid = min(128, kNTokL - tile * 128);
  const size_t xbase = ((size_t)b * kNTokL + (size_t)tile * 128) * kC;
  const int wid = tid >> 6, lane = tid & 63;
  const int wm = wid >> 1, wn = wid & 1;
  const int fm = lane & 15;
  const int kq = (lane >> 4) * 8;
  floatx4 acc[4][4];
#pragma unroll
  for (int i = 0; i < 4; ++i)
#pragma unroll
    for (int j = 0; j < 4; ++j) acc[i][j] = (floatx4){0.f, 0.f, 0.f, 0.f};
  const int r = tid >> 1;
  const int kh = (tid & 1) * 16;
  for (int kc = 0; kc < kC; kc += 32) {
    {
      float4 f[4] = {};
      if (r < valid) {
        const float* p = lf + xbase + (size_t)r * kC + kc + kh;
#pragma unroll
        for (int q = 0; q < 4; ++q) f[q] = *(const float4*)(p + q * 4);
      }
      S8U h0, h1, l0, l1;
      const float* fs = (const float*)f;
#pragma unroll
      for (int e = 0; e < 8; ++e) bsplit(fs[e], h0.u[e], l0.u[e]);
#pragma unroll
      for (int e = 0; e < 8; ++e) bsplit(fs[8 + e], h1.u[e], l1.u[e]);
      *(short8*)&Ah[r * LDSTR + kh] = h0.v;
      *(short8*)&Ah[r * LDSTR + kh + 8] = h1.v;
      *(short8*)&Al[r * LDSTR + kh] = l0.v;
      *(short8*)&Al[r * LDSTR + kh + 8] = l1.v;
    }
    {
      const ushort* ph = Wh + (size_t)(dbase + r) * kC + kc + kh;
      const ushort* pl = Wl + (size_t)(dbase + r) * kC + kc + kh;
      float4 bh0 = *(const float4*)ph;
      float4 bh1 = *(const float4*)(ph + 8);
      float4 bl0 = *(const float4*)pl;
      float4 bl1 = *(const float4*)(pl + 8);
      *(float4*)&Bh[r * LDSTR + kh] = bh0;
      *(float4*)&Bh[r * LDSTR + kh + 8] = bh1;
      *(float4*)&Bl[r * LDSTR + kh] = bl0;
      *(float4*)&Bl[r * LDSTR + kh + 8] = bl1;
    }
    __syncthreads();
    short8 ah[4], al[4], bh[4], bl[4];
#pragma unroll
    for (int t = 0; t < 4; ++t) {
      ah[t] = *(const short8*)&Ah[(wm * 64 + t * 16 + fm) * LDSTR + kq];
      al[t] = *(const short8*)&Al[(wm * 64 + t * 16 + fm) * LDSTR + kq];
      bh[t] = *(const short8*)&Bh[(wn * 64 + t * 16 + fm) * LDSTR + kq];
      bl[t] = *(const short8*)&Bl[(wn * 64 + t * 16 + fm) * LDSTR + kq];
    }
#pragma unroll
    for (int mt = 0; mt < 4; ++mt)
#pragma unroll
      for (int nt = 0; nt < 4; ++nt) {
        acc[mt][nt] = MFMA_BF16(ah[mt], bh[nt], acc[mt][nt]);
        acc[mt][nt] = MFMA_BF16(al[mt], bh[nt], acc[mt][nt]);
        acc[mt][nt] = MFMA_BF16(ah[mt], bl[nt], acc[mt][nt]);
      }
    __syncthreads();
  }
  float mv[4], gv[5][4];
#pragma unroll
  for (int nt = 0; nt < 4; ++nt) {
    const int d = dbase + wn * 64 + nt * 16 + fm;
    mv[nt] = m[b * kC + d];
#pragma unroll
    for (int g = 0; g < 5; ++g) gv[g][nt] = gn[(b * kNG + g) * kC + d];
  }
#pragma unroll
  for (int mt = 0; mt < 4; ++mt)
#pragma unroll
    for (int reg = 0; reg < 4; ++reg) {
      float part[6] = {0.f, 0.f, 0.f, 0.f, 0.f, 0.f};
#pragma unroll
      for (int nt = 0; nt < 4; ++nt) {
        const float yc = acc[mt][nt][reg] - mv[nt];
        part[0] += yc * yc;
#pragma unroll
        for (int g = 0; g < 5; ++g) part[1 + g] += yc * gv[g][nt];
      }
#pragma unroll
      for (int off = 1; off < 16; off <<= 1)
#pragma unroll
        for (int v = 0; v < 6; ++v) part[v] += __shfl_xor(part[v], off);
      const int row128 = wm * 64 + mt * 16 + (lane >> 4) * 4 + reg;
      if (fm == 0 && row128 < valid) {
        const size_t t = (size_t)b * kNTokL + (size_t)tile * 128 + row128;
        atomicAdd(&nsq[t], part[0]);
#pragma unroll
        for (int g = 0; g < 5; ++g)
          atomicAdd(&dots[(size_t)g * (kB * kNTokL) + t], part[1 + g]);
      }
    }
}

// ===================== launcher =====================

extern "C" void kernel_launch(void* const* d_in, const int* in_sizes, int n_in,
                              void* d_out, int out_size, void* d_ws, size_t ws_size,
                              hipStream_t stream) {
  (void)in_sizes; (void)n_in; (void)out_size;
  const float* gf = (const float*)d_in[0];
  const float* lf = (const float*)d_in[1];
  const float* Wq = (const float*)d_in[2];
  const float* Wk = (const float*)d_in[3];
  float* ws = (float*)d_ws;
  float* out = (float*)d_out;

  // common small buffers (float offsets)
  float* s_l  = ws;             // 5120
  float* m    = ws + 5120;      // 5120
  float* gc   = ws + 10240;     // 25600
  float* gn   = ws + 35840;     // 25600
  float* nsq  = ws + 61440;     // 117600
  float* dots = ws + 179040;    // 588000
  // main-path fragment buffers
  ushort* Whf = (ushort*)(ws + 767040);    // 409600 shorts
  ushort* Wlf = (ushort*)(ws + 971840);    // 409600 shorts
  ushort* Xhf = (ushort*)(ws + 1176640);   // 8*920*20*512 = 75366400 shorts
  ushort* Xlf = (ushort*)(ws + 38859840);  // 75366400 shorts
  const size_t needed = (size_t)76543040 * 4;  // ~306.2 MB

  hipMemsetAsync(s_l, 0, (size_t)5120 * 4, stream);
  hipMemsetAsync(nsq, 0, (size_t)(117600 + 588000) * 4, stream);

  if (ws_size >= needed) {
    k_prep<<<dim3(10, kKC, kB), 256, 0, stream>>>(lf, Xhf, Xlf, s_l);
    k_cvtW_frag<<<400, 256, 0, stream>>>(Wk, Whf, Wlf);
    k_proj_mean<<<(kB * kC) / 4, 256, 0, stream>>>(Wq, Wk, gf, s_l, m, gc);
    k_norm_g<<<kB * kNG, 256, 0, stream>>>(gc, gn);
    k_big<<<115 * 40, 256, 0, stream>>>(Xhf, Xlf, Whf, Wlf, m, gn, nsq, dots);
  } else {
    // fallback: R2 structure (ws ~3.9 MB)
    ushort* Wh2 = (ushort*)(ws + 767040);
    ushort* Wl2 = (ushort*)(ws + 767040 + 204800);
    fb_sum_local<<<dim3(kB, 32), kC, 0, stream>>>(lf, s_l);
    fb_cvtW<<<1600, 256, 0, stream>>>(Wk, Wh2, Wl2);
    k_proj_mean<<<(kB * kC) / 4, 256, 0, stream>>>(Wq, Wk, gf, s_l, m, gc);
    k_norm_g<<<kB * kNG, 256, 0, stream>>>(gc, gn);
    fb_big<<<dim3(5, 115, kB), 256, 0, stream>>>(lf, Wh2, Wl2, m, gn, nsq, dots);
  }
  k_softmax<<<750, 256, 0, stream>>>(nsq, dots, out);
}

// Round 4
// 891.506 us; speedup vs baseline: 1.8063x; 1.0484x over previous
//
#include <hip/hip_runtime.h>
#include <math.h>

namespace {
constexpr int kB = 8, kNG = 5, kNL = 75, kNF = 196, kC = 640;
constexpr int kNTokL = kNL * kNF;      // 14700
constexpr int kNTot = kNG + kNTokL;    // 14705
constexpr float kEps = 1e-12f;
constexpr float kInvAlpha = 10.0f;
constexpr int kKC = 20;                // 640 / 32 K-chunks
constexpr int kTiles = 230;            // ceil(14700 / 64) 64-token tiles per batch
}

typedef __attribute__((ext_vector_type(8))) short short8;
typedef __attribute__((ext_vector_type(4))) float floatx4;

union S8U { short8 v; ushort u[8]; };

// round-to-nearest-even bf16 split: x ~= hi + lo
__device__ __forceinline__ void bsplit(float x, ushort& h, ushort& l) {
  union { float f; uint u; } a; a.f = x;
  uint uh = (a.u + 0x7FFFu + ((a.u >> 16) & 1u)) >> 16;
  h = (ushort)uh;
  union { uint u; float f; } bb; bb.u = uh << 16;
  float r = x - bb.f;
  union { float f; uint u; } c; c.f = r;
  l = (ushort)((c.u + 0x7FFFu + ((c.u >> 16) & 1u)) >> 16);
}

#define MFMA_BF16(a, b, c) __builtin_amdgcn_mfma_f32_16x16x32_bf16(a, b, c, 0, 0, 0)

// barrier that does NOT drain vmcnt (keeps global prefetches in flight).
// waits only LDS ops; memory clobber pins compiler-level ordering.
__device__ __forceinline__ void bar_lds() {
  asm volatile("s_waitcnt lgkmcnt(0)\n\ts_barrier" ::: "memory");
}

// ---------- small kernels ----------

// s_l[b,c] = sum_t local_f[b,t,c]
__global__ void k_sum_local(const float* __restrict__ lf, float* __restrict__ s_l) {
  const int b = blockIdx.x, s = blockIdx.y, c = threadIdx.x;  // block = 640 threads
  const int t0 = s * 460, t1 = min(t0 + 460, kNTokL);
  const float* p = lf + ((size_t)b * kNTokL) * kC + c;
  float acc = 0.f;
  for (int t = t0; t < t1; ++t) acc += p[(size_t)t * kC];
  atomicAdd(&s_l[b * kC + c], acc);
}

// Wk -> Wh/Wl in lane-major MFMA frag tiles: tile (dt,kc) = 512 shorts,
// lane l (l = quad*16 + n) holds W[d = dt*16+n][k = kc*32 + quad*8 .. +8].
__global__ void k_cvtW(const float* __restrict__ Wk, ushort* __restrict__ Wh,
                       ushort* __restrict__ Wl) {
  const int wv = blockIdx.x * 4 + (threadIdx.x >> 6);  // 0..799 = 40 dt x 20 kc
  const int lane = threadIdx.x & 63;
  const int kc = wv % kKC, dt = wv / kKC;
  const int fm = lane & 15, quad = lane >> 4;
  const float* p = Wk + (size_t)(dt * 16 + fm) * kC + kc * 32 + quad * 8;
  float4 a = *(const float4*)p;
  float4 c = *(const float4*)(p + 4);
  S8U h, l;
  bsplit(a.x, h.u[0], l.u[0]); bsplit(a.y, h.u[1], l.u[1]);
  bsplit(a.z, h.u[2], l.u[2]); bsplit(a.w, h.u[3], l.u[3]);
  bsplit(c.x, h.u[4], l.u[4]); bsplit(c.y, h.u[5], l.u[5]);
  bsplit(c.z, h.u[6], l.u[6]); bsplit(c.w, h.u[7], l.u[7]);
  const size_t off = ((size_t)dt * kKC + kc) * 512 + (size_t)lane * 8;
  *(short8*)(Wh + off) = h.v;
  *(short8*)(Wl + off) = l.v;
}

// One wave per (b,d): m[b,d] = (Wq[d]·sum_g gf + Wk[d]·s_l[b]) / 14705
// gc[b,g,d] = Wq[d]·gf[b,g] - m[b,d]
__global__ void k_proj_mean(const float* __restrict__ Wq, const float* __restrict__ Wk,
                            const float* __restrict__ gf, const float* __restrict__ s_l,
                            float* __restrict__ m, float* __restrict__ gc) {
  const int wid = blockIdx.x * 4 + (threadIdx.x >> 6);
  const int lane = threadIdx.x & 63;
  const int b = wid / kC, d = wid % kC;
  float ak = 0.f, ag[kNG] = {0.f, 0.f, 0.f, 0.f, 0.f};
  for (int c = lane; c < kC; c += 64) {
    const float wq = Wq[d * kC + c];
    const float wk = Wk[d * kC + c];
    ak += wk * s_l[b * kC + c];
#pragma unroll
    for (int g = 0; g < kNG; ++g) ag[g] += wq * gf[(b * kNG + g) * kC + c];
  }
#pragma unroll
  for (int off = 32; off > 0; off >>= 1) {
    ak += __shfl_xor(ak, off);
#pragma unroll
    for (int g = 0; g < kNG; ++g) ag[g] += __shfl_xor(ag[g], off);
  }
  if (lane == 0) {
    float aq = 0.f;
#pragma unroll
    for (int g = 0; g < kNG; ++g) aq += ag[g];
    const float mv = (aq + ak) / (float)kNTot;
    m[b * kC + d] = mv;
#pragma unroll
    for (int g = 0; g < kNG; ++g) gc[(b * kNG + g) * kC + d] = ag[g] - mv;
  }
}

__global__ void k_norm_g(const float* __restrict__ gc, float* __restrict__ gn) {
  const int row = blockIdx.x;
  __shared__ float red[256];
  float a = 0.f;
  for (int d = threadIdx.x; d < kC; d += 256) {
    const float v = gc[row * kC + d];
    a += v * v;
  }
  red[threadIdx.x] = a;
  __syncthreads();
  for (int s = 128; s > 0; s >>= 1) {
    if (threadIdx.x < s) red[threadIdx.x] += red[threadIdx.x + s];
    __syncthreads();
  }
  const float rs = 1.0f / sqrtf(red[0] + kEps);
  for (int d = threadIdx.x; d < kC; d += 256) gn[row * kC + d] = gc[row * kC + d] * rs;
}

// ---------- the big fused kernel ----------
// Block = 64 tokens x ALL 640 d. 4 waves (wn = wave id), wave = 64 tok x 160 d.
// Per K-chunk: stage 64x32 fp32 A -> bf16 hi/lo frag tiles in LDS (once);
// B frags stream direct from L2-resident Wh/Wl with 1-tile prefetch.
// Epilogue: full-d reduction in-block -> write FINAL scores (no atomics).
__global__ __launch_bounds__(256, 2) void k_big(
    const float* __restrict__ lf, const ushort* __restrict__ Wh,
    const ushort* __restrict__ Wl, const float* __restrict__ m,
    const float* __restrict__ gn, float* __restrict__ scores) {
  __shared__ char smem[8192];            // Ah 4KB | Al 4KB ; epilogue red 6KB reuses
  ushort* Ah = (ushort*)smem;
  ushort* Al = (ushort*)(smem + 4096);
  float* red = (float*)smem;             // [wn][64 rows][6]

  const int tid = threadIdx.x;
  const int wn = tid >> 6, lane = tid & 63;
  const int fm = lane & 15, quad = lane >> 4;
  const int b = blockIdx.x & 7, tile = blockIdx.x >> 3;
  const int tok0 = tile * 64;

  // staging role: token row sr (0..63), k-quad sq (0..3) -> 8 floats
  const int sr = tid >> 2, sq = tid & 3;
  const int st = tok0 + sr;
  const bool sok = st < kNTokL;
  const float* xrow = lf + ((size_t)b * kNTokL + st) * kC + sq * 8;
  ushort* ah_w = Ah + (sr >> 4) * 512 + (size_t)(sq * 16 + (sr & 15)) * 8;
  ushort* al_w = Al + (sr >> 4) * 512 + (size_t)(sq * 16 + (sr & 15)) * 8;

  const ushort* bhbase = Wh + ((size_t)wn * 10 * kKC) * 512 + (size_t)lane * 8;
  const ushort* blbase = Wl + ((size_t)wn * 10 * kKC) * 512 + (size_t)lane * 8;

  floatx4 acc[4][10];
#pragma unroll
  for (int i = 0; i < 4; ++i)
#pragma unroll
    for (int j = 0; j < 10; ++j) acc[i][j] = (floatx4){0.f, 0.f, 0.f, 0.f};

  float4 xa = {0.f, 0.f, 0.f, 0.f}, xb = {0.f, 0.f, 0.f, 0.f};
  if (sok) { xa = *(const float4*)xrow; xb = *(const float4*)(xrow + 4); }

  for (int kc = 0; kc < kKC; ++kc) {
    const float4 ca = xa, cb = xb;
    if (kc + 1 < kKC && sok) {               // register prefetch next A chunk
      xa = *(const float4*)(xrow + (kc + 1) * 32);
      xb = *(const float4*)(xrow + (kc + 1) * 32 + 4);
    }
    // prefetch first B tile of this chunk (in flight across the barriers)
    short8 bh_n = *(const short8*)(bhbase + (size_t)kc * 512);
    short8 bl_n = *(const short8*)(blbase + (size_t)kc * 512);

    bar_lds();  // previous chunk's ds_reads done before LDS overwrite
    {
      S8U h, l;
      bsplit(ca.x, h.u[0], l.u[0]); bsplit(ca.y, h.u[1], l.u[1]);
      bsplit(ca.z, h.u[2], l.u[2]); bsplit(ca.w, h.u[3], l.u[3]);
      bsplit(cb.x, h.u[4], l.u[4]); bsplit(cb.y, h.u[5], l.u[5]);
      bsplit(cb.z, h.u[6], l.u[6]); bsplit(cb.w, h.u[7], l.u[7]);
      *(short8*)ah_w = h.v;
      *(short8*)al_w = l.v;
    }
    bar_lds();  // staged data visible

    short8 ah[4], al[4];
#pragma unroll
    for (int mt = 0; mt < 4; ++mt) {
      ah[mt] = *(const short8*)(Ah + mt * 512 + (size_t)lane * 8);
      al[mt] = *(const short8*)(Al + mt * 512 + (size_t)lane * 8);
    }
#pragma unroll
    for (int nt = 0; nt < 10; ++nt) {
      const short8 bh_c = bh_n, bl_c = bl_n;
      if (nt + 1 < 10) {
        bh_n = *(const short8*)(bhbase + (size_t)((nt + 1) * kKC + kc) * 512);
        bl_n = *(const short8*)(blbase + (size_t)((nt + 1) * kKC + kc) * 512);
      }
#pragma unroll
      for (int mt = 0; mt < 4; ++mt) {
        acc[mt][nt] = MFMA_BF16(ah[mt], bh_c, acc[mt][nt]);
        acc[mt][nt] = MFMA_BF16(al[mt], bh_c, acc[mt][nt]);
        acc[mt][nt] = MFMA_BF16(ah[mt], bl_c, acc[mt][nt]);
      }
    }
  }

  // ---- epilogue: center, reduce over this wave's 160 d, combine 4 waves ----
  float mv[10], gvv[5][10];
#pragma unroll
  for (int nt = 0; nt < 10; ++nt) {
    const int d = wn * 160 + nt * 16 + fm;
    mv[nt] = m[b * kC + d];
#pragma unroll
    for (int g = 0; g < 5; ++g) gvv[g][nt] = gn[(b * kNG + g) * kC + d];
  }

  bar_lds();  // all waves' ds_reads done before red[] overwrites Ah/Al
#pragma unroll
  for (int mt = 0; mt < 4; ++mt)
#pragma unroll
    for (int reg = 0; reg < 4; ++reg) {
      float part[6] = {0.f, 0.f, 0.f, 0.f, 0.f, 0.f};
#pragma unroll
      for (int nt = 0; nt < 10; ++nt) {
        const float yc = acc[mt][nt][reg] - mv[nt];
        part[0] += yc * yc;
#pragma unroll
        for (int g = 0; g < 5; ++g) part[1 + g] += yc * gvv[g][nt];
      }
#pragma unroll
      for (int off = 1; off < 16; off <<= 1)
#pragma unroll
        for (int v = 0; v < 6; ++v) part[v] += __shfl_xor(part[v], off);
      if (fm == 0) {
        const int row = mt * 16 + quad * 4 + reg;
#pragma unroll
        for (int v = 0; v < 6; ++v) red[((size_t)wn * 64 + row) * 6 + v] = part[v];
      }
    }
  bar_lds();
  if (tid < 64) {
    const int tok = tok0 + tid;
    if (tok < kNTokL) {
      float s[6] = {0.f, 0.f, 0.f, 0.f, 0.f, 0.f};
#pragma unroll
      for (int w = 0; w < 4; ++w)
#pragma unroll
        for (int v = 0; v < 6; ++v) s[v] += red[((size_t)w * 64 + tid) * 6 + v];
      const float rs = (1.0f / sqrtf(s[0] + kEps)) * kInvAlpha;
      const size_t t = (size_t)b * kNTokL + tok;
#pragma unroll
      for (int g = 0; g < 5; ++g)
        scores[(size_t)g * (kB * kNTokL) + t] = s[1 + g] * rs;
    }
  }
}

// softmax over f (196) per (b,l,g) row; one wave per row. scores pre-scaled.
__global__ void k_softmax(const float* __restrict__ scores, float* __restrict__ out) {
  const int wid = blockIdx.x * 4 + (threadIdx.x >> 6);
  const int lane = threadIdx.x & 63;
  const int b = wid / (kNL * kNG);
  const int rem = wid % (kNL * kNG);
  const int l = rem / kNG, g = rem % kNG;
  float sv[4];
  float mx = -1e30f;
#pragma unroll
  for (int u = 0; u < 4; ++u) {
    const int f = lane + 64 * u;
    if (f < kNF) {
      const size_t t = (size_t)b * kNTokL + (size_t)l * kNF + f;
      sv[u] = scores[(size_t)g * (kB * kNTokL) + t];
      mx = fmaxf(mx, sv[u]);
    } else {
      sv[u] = 0.f;
    }
  }
#pragma unroll
  for (int off = 32; off > 0; off >>= 1) mx = fmaxf(mx, __shfl_xor(mx, off));
  float se = 0.f;
#pragma unroll
  for (int u = 0; u < 4; ++u) {
    const int f = lane + 64 * u;
    const float e = (f < kNF) ? expf(sv[u] - mx) : 0.f;
    sv[u] = e;
    se += e;
  }
#pragma unroll
  for (int off = 32; off > 0; off >>= 1) se += __shfl_xor(se, off);
  const float inv = 1.0f / se;
#pragma unroll
  for (int u = 0; u < 4; ++u) {
    const int f = lane + 64 * u;
    if (f < kNF) out[((size_t)(b * kNL + l) * kNG + g) * kNF + f] = sv[u] * inv;
  }
}

// ===================== launcher =====================

extern "C" void kernel_launch(void* const* d_in, const int* in_sizes, int n_in,
                              void* d_out, int out_size, void* d_ws, size_t ws_size,
                              hipStream_t stream) {
  (void)in_sizes; (void)n_in; (void)out_size; (void)ws_size;
  const float* gf = (const float*)d_in[0];  // [8,5,640]
  const float* lf = (const float*)d_in[1];  // [8,75,196,640]
  const float* Wq = (const float*)d_in[2];  // [640,640]
  const float* Wk = (const float*)d_in[3];  // [640,640]
  float* ws = (float*)d_ws;
  float* out = (float*)d_out;

  // workspace (float offsets): total ~4.1 MB
  float* s_l    = ws;            // 5120
  float* m      = ws + 5120;     // 5120
  float* gc     = ws + 10240;    // 25600
  float* gn     = ws + 35840;    // 25600
  float* scores = ws + 61440;    // 5*117600 = 588000  (layout [g][t])
  ushort* Wh    = (ushort*)(ws + 649440);  // 409600 shorts
  ushort* Wl    = (ushort*)(ws + 854240);  // 409600 shorts

  hipMemsetAsync(s_l, 0, (size_t)5120 * 4, stream);

  k_sum_local<<<dim3(kB, 32), kC, 0, stream>>>(lf, s_l);
  k_cvtW<<<200, 256, 0, stream>>>(Wk, Wh, Wl);
  k_proj_mean<<<(kB * kC) / 4, 256, 0, stream>>>(Wq, Wk, gf, s_l, m, gc);
  k_norm_g<<<kB * kNG, 256, 0, stream>>>(gc, gn);
  k_big<<<kTiles * kB, 256, 0, stream>>>(lf, Wh, Wl, m, gn, scores);
  k_softmax<<<750, 256, 0, stream>>>(scores, out);
}

// Round 5
// 766.079 us; speedup vs baseline: 2.1020x; 1.1637x over previous
//
#include <hip/hip_runtime.h>
#include <math.h>

namespace {
constexpr int kB = 8, kNG = 5, kNL = 75, kNF = 196, kC = 640;
constexpr int kNTokL = kNL * kNF;      // 14700
constexpr int kNTot = kNG + kNTokL;    // 14705
constexpr float kEps = 1e-12f;
constexpr float kInvAlpha = 10.0f;
constexpr int kKC = 20;                // 640 / 32 K-chunks
constexpr int kTiles = 230;            // 64-token tiles per batch
constexpr int kNT = 5;                 // 16-d tiles per wave (wave = 64 tok x 80 d)
}

typedef __attribute__((ext_vector_type(8))) short short8;
typedef __attribute__((ext_vector_type(4))) short short4v;
typedef __attribute__((ext_vector_type(4))) float floatx4;

union S8U { short8 v; ushort u[8]; };
union S4U { short4v v; ushort u[4]; };

// round-to-nearest-even bf16 split: x ~= hi + lo
__device__ __forceinline__ void bsplit(float x, ushort& h, ushort& l) {
  union { float f; uint u; } a; a.f = x;
  uint uh = (a.u + 0x7FFFu + ((a.u >> 16) & 1u)) >> 16;
  h = (ushort)uh;
  union { uint u; float f; } bb; bb.u = uh << 16;
  float r = x - bb.f;
  union { float f; uint u; } c; c.f = r;
  l = (ushort)((c.u + 0x7FFFu + ((c.u >> 16) & 1u)) >> 16);
}

#define MFMA_BF16(a, b, c) __builtin_amdgcn_mfma_f32_16x16x32_bf16(a, b, c, 0, 0, 0)

// barrier that does NOT drain vmcnt (keeps global prefetches in flight)
__device__ __forceinline__ void bar_lds() {
  asm volatile("s_waitcnt lgkmcnt(0)\n\ts_barrier" ::: "memory");
}

// ---------- small kernels ----------

// s_l[b,c] = sum_t local_f[b,t,c]. grid (8,64), block 320 (float4 per lane).
__global__ void k_sum_local(const float* __restrict__ lf, float* __restrict__ s_l) {
  const int b = blockIdx.x, slice = blockIdx.y;
  const int tid = threadIdx.x;
  const int c4 = tid % 160, h = tid / 160;       // column group, row half
  const int t0 = slice * 230 + h * 115;
  const int nrow = min(115, kNTokL - t0);
  const float* p = lf + ((size_t)b * kNTokL + t0) * kC + c4 * 4;
  float4 acc = {0.f, 0.f, 0.f, 0.f};
  for (int i = 0; i < nrow; ++i) {
    const float4 v = *(const float4*)(p + (size_t)i * kC);
    acc.x += v.x; acc.y += v.y; acc.z += v.z; acc.w += v.w;
  }
  float* dst = &s_l[b * kC + c4 * 4];
  atomicAdd(dst + 0, acc.x);
  atomicAdd(dst + 1, acc.y);
  atomicAdd(dst + 2, acc.z);
  atomicAdd(dst + 3, acc.w);
}

// Wk -> Wh/Wl in lane-major MFMA frag tiles: tile (dt,kc) = 512 shorts,
// lane l (l = quad*16 + n) holds W[d = dt*16+n][k = kc*32 + quad*8 .. +8].
__global__ void k_cvtW(const float* __restrict__ Wk, ushort* __restrict__ Wh,
                       ushort* __restrict__ Wl) {
  const int wv = blockIdx.x * 4 + (threadIdx.x >> 6);  // 0..799 = 40 dt x 20 kc
  const int lane = threadIdx.x & 63;
  const int kc = wv % kKC, dt = wv / kKC;
  const int fm = lane & 15, quad = lane >> 4;
  const float* p = Wk + (size_t)(dt * 16 + fm) * kC + kc * 32 + quad * 8;
  float4 a = *(const float4*)p;
  float4 c = *(const float4*)(p + 4);
  S8U h, l;
  bsplit(a.x, h.u[0], l.u[0]); bsplit(a.y, h.u[1], l.u[1]);
  bsplit(a.z, h.u[2], l.u[2]); bsplit(a.w, h.u[3], l.u[3]);
  bsplit(c.x, h.u[4], l.u[4]); bsplit(c.y, h.u[5], l.u[5]);
  bsplit(c.z, h.u[6], l.u[6]); bsplit(c.w, h.u[7], l.u[7]);
  const size_t off = ((size_t)dt * kKC + kc) * 512 + (size_t)lane * 8;
  *(short8*)(Wh + off) = h.v;
  *(short8*)(Wl + off) = l.v;
}

// One wave per (b,d): m[b,d] = (Wq[d]·sum_g gf + Wk[d]·s_l[b]) / 14705
// gc[b,g,d] = Wq[d]·gf[b,g] - m[b,d]
__global__ void k_proj_mean(const float* __restrict__ Wq, const float* __restrict__ Wk,
                            const float* __restrict__ gf, const float* __restrict__ s_l,
                            float* __restrict__ m, float* __restrict__ gc) {
  const int wid = blockIdx.x * 4 + (threadIdx.x >> 6);
  const int lane = threadIdx.x & 63;
  const int b = wid / kC, d = wid % kC;
  float ak = 0.f, ag[kNG] = {0.f, 0.f, 0.f, 0.f, 0.f};
  for (int c = lane; c < kC; c += 64) {
    const float wq = Wq[d * kC + c];
    const float wk = Wk[d * kC + c];
    ak += wk * s_l[b * kC + c];
#pragma unroll
    for (int g = 0; g < kNG; ++g) ag[g] += wq * gf[(b * kNG + g) * kC + c];
  }
#pragma unroll
  for (int off = 32; off > 0; off >>= 1) {
    ak += __shfl_xor(ak, off);
#pragma unroll
    for (int g = 0; g < kNG; ++g) ag[g] += __shfl_xor(ag[g], off);
  }
  if (lane == 0) {
    float aq = 0.f;
#pragma unroll
    for (int g = 0; g < kNG; ++g) aq += ag[g];
    const float mv = (aq + ak) / (float)kNTot;
    m[b * kC + d] = mv;
#pragma unroll
    for (int g = 0; g < kNG; ++g) gc[(b * kNG + g) * kC + d] = ag[g] - mv;
  }
}

__global__ void k_norm_g(const float* __restrict__ gc, float* __restrict__ gn) {
  const int row = blockIdx.x;
  __shared__ float red[256];
  float a = 0.f;
  for (int d = threadIdx.x; d < kC; d += 256) {
    const float v = gc[row * kC + d];
    a += v * v;
  }
  red[threadIdx.x] = a;
  __syncthreads();
  for (int s = 128; s > 0; s >>= 1) {
    if (threadIdx.x < s) red[threadIdx.x] += red[threadIdx.x + s];
    __syncthreads();
  }
  const float rs = 1.0f / sqrtf(red[0] + kEps);
  for (int d = threadIdx.x; d < kC; d += 256) gn[row * kC + d] = gc[row * kC + d] * rs;
}

// ---------- the big fused kernel ----------
// Block = 64 tokens x ALL 640 d. 8 waves, wave wn = 64 tok x 80 d (5 nt tiles).
// Per K-chunk: full B fragment set in registers, double-buffered, prefetched
// ONE FULL CHUNK ahead; A globals prefetched two chunks ahead, staged to
// double-buffered LDS (one non-draining barrier per chunk).
__global__ __launch_bounds__(512, 1) void k_big(
    const float* __restrict__ lf, const ushort* __restrict__ Wh,
    const ushort* __restrict__ Wl, const float* __restrict__ m,
    const float* __restrict__ gn, float* __restrict__ scores) {
  __shared__ char smem[16384];  // buf p: Ah @ p*8192, Al @ p*8192+4096; red overlays
  ushort* Ah0 = (ushort*)smem;
  ushort* Al0 = (ushort*)(smem + 4096);
  ushort* Ah1 = (ushort*)(smem + 8192);
  ushort* Al1 = (ushort*)(smem + 12288);
  float* red = (float*)smem;  // [8 waves][64 rows][6]

  const int tid = threadIdx.x;
  const int wn = tid >> 6, lane = tid & 63;
  const int fm = lane & 15, quad = lane >> 4;
  const int b = blockIdx.x & 7, tile = blockIdx.x >> 3;
  const int tok0 = tile * 64;

  // staging role: token row sr (0..63), float4 col group sq (0..7)
  const int sr = tid >> 3, sq = tid & 7;
  const int st = tok0 + sr;
  const bool sok = st < kNTokL;
  const float* xrow = lf + ((size_t)b * kNTokL + st) * kC + sq * 4;
  // frag-tile offset (shorts): tile (sr>>4), lane' = (sq>>1)*16 + (sr&15), j = (sq&1)*4
  const int aoff = ((sr >> 4) << 9) + (((sq >> 1) * 16 + (sr & 15)) << 3) + ((sq & 1) << 2);

  const ushort* bhbase = Wh + ((size_t)wn * kNT * kKC) * 512 + (size_t)lane * 8;
  const ushort* blbase = Wl + ((size_t)wn * kNT * kKC) * 512 + (size_t)lane * 8;

  floatx4 acc[4][kNT];
#pragma unroll
  for (int i = 0; i < 4; ++i)
#pragma unroll
    for (int j = 0; j < kNT; ++j) acc[i][j] = (floatx4){0.f, 0.f, 0.f, 0.f};

#define STAGE_A(XV, AH, AL)                                   \
  {                                                           \
    S4U _h, _l;                                               \
    bsplit((XV).x, _h.u[0], _l.u[0]);                         \
    bsplit((XV).y, _h.u[1], _l.u[1]);                         \
    bsplit((XV).z, _h.u[2], _l.u[2]);                         \
    bsplit((XV).w, _h.u[3], _l.u[3]);                         \
    *(short4v*)((AH) + aoff) = _h.v;                          \
    *(short4v*)((AL) + aoff) = _l.v;                          \
  }

#define LOADB(BH, BL, KCI)                                                        \
  {                                                                               \
    _Pragma("unroll") for (int nt = 0; nt < kNT; ++nt) {                          \
      BH[nt] = *(const short8*)(bhbase + ((size_t)nt * kKC + (KCI)) * 512);       \
      BL[nt] = *(const short8*)(blbase + ((size_t)nt * kKC + (KCI)) * 512);       \
    }                                                                             \
  }

#define READA(AH, AL)                                                  \
  {                                                                    \
    _Pragma("unroll") for (int mt = 0; mt < 4; ++mt) {                 \
      ah[mt] = *(const short8*)((AH) + mt * 512 + lane * 8);           \
      al[mt] = *(const short8*)((AL) + mt * 512 + lane * 8);           \
    }                                                                  \
  }

#define DOMFMA(BH, BL)                                                 \
  {                                                                    \
    _Pragma("unroll") for (int nt = 0; nt < kNT; ++nt)                 \
        _Pragma("unroll") for (int mt = 0; mt < 4; ++mt) {             \
      acc[mt][nt] = MFMA_BF16(ah[mt], BH[nt], acc[mt][nt]);            \
      acc[mt][nt] = MFMA_BF16(al[mt], BH[nt], acc[mt][nt]);            \
      acc[mt][nt] = MFMA_BF16(ah[mt], BL[nt], acc[mt][nt]);            \
    }                                                                  \
  }

  const float4 fzero = {0.f, 0.f, 0.f, 0.f};
  // chunk 0: load + stage into buf0
  float4 x0 = sok ? *(const float4*)xrow : fzero;
  STAGE_A(x0, Ah0, Al0);
  // chunk 1 globals (consumed by staging at even iter 0)
  float4 xA = sok ? *(const float4*)(xrow + 32) : fzero;
  float4 xB = fzero;
  // B chunk 0
  short8 BH0[kNT], BL0[kNT], BH1[kNT], BL1[kNT];
  LOADB(BH0, BL0, 0);

  short8 ah[4], al[4];
  for (int kc = 0; kc < kKC; kc += 2) {
    // ---- even iter: compute chunk kc (buf0, BH0) ----
    bar_lds();
    READA(Ah0, Al0);
    LOADB(BH1, BL1, kc + 1);                       // B for kc+1 (always exists)
    if (sok && kc + 2 < kKC) xB = *(const float4*)(xrow + (kc + 2) * 32);
    STAGE_A(xA, Ah1, Al1);                         // A chunk kc+1 -> buf1
    DOMFMA(BH0, BL0);

    // ---- odd iter: compute chunk kc+1 (buf1, BH1) ----
    bar_lds();
    READA(Ah1, Al1);
    if (kc + 2 < kKC) {
      LOADB(BH0, BL0, kc + 2);
      if (sok && kc + 3 < kKC) xA = *(const float4*)(xrow + (kc + 3) * 32);
      STAGE_A(xB, Ah0, Al0);                       // A chunk kc+2 -> buf0
    }
    DOMFMA(BH1, BL1);
  }

  // ---- epilogue: center, reduce over d, combine 8 waves, write scores ----
  float mv[kNT], gvv[5][kNT];
#pragma unroll
  for (int nt = 0; nt < kNT; ++nt) {
    const int d = wn * 80 + nt * 16 + fm;
    mv[nt] = m[b * kC + d];
#pragma unroll
    for (int g = 0; g < 5; ++g) gvv[g][nt] = gn[(b * kNG + g) * kC + d];
  }

  bar_lds();  // all waves' K-loop ds_reads done before red[] overwrites bufs
#pragma unroll
  for (int mt = 0; mt < 4; ++mt)
#pragma unroll
    for (int reg = 0; reg < 4; ++reg) {
      float part[6] = {0.f, 0.f, 0.f, 0.f, 0.f, 0.f};
#pragma unroll
      for (int nt = 0; nt < kNT; ++nt) {
        const float yc = acc[mt][nt][reg] - mv[nt];
        part[0] += yc * yc;
#pragma unroll
        for (int g = 0; g < 5; ++g) part[1 + g] += yc * gvv[g][nt];
      }
#pragma unroll
      for (int off = 1; off < 16; off <<= 1)
#pragma unroll
        for (int v = 0; v < 6; ++v) part[v] += __shfl_xor(part[v], off);
      if (fm == 0) {
        const int row = mt * 16 + quad * 4 + reg;
#pragma unroll
        for (int v = 0; v < 6; ++v) red[((size_t)wn * 64 + row) * 6 + v] = part[v];
      }
    }
  bar_lds();
  if (tid < 64) {
    const int tok = tok0 + tid;
    if (tok < kNTokL) {
      float s[6] = {0.f, 0.f, 0.f, 0.f, 0.f, 0.f};
#pragma unroll
      for (int w = 0; w < 8; ++w)
#pragma unroll
        for (int v = 0; v < 6; ++v) s[v] += red[((size_t)w * 64 + tid) * 6 + v];
      const float rs = (1.0f / sqrtf(s[0] + kEps)) * kInvAlpha;
      const size_t t = (size_t)b * kNTokL + tok;
#pragma unroll
      for (int g = 0; g < 5; ++g)
        scores[(size_t)g * (kB * kNTokL) + t] = s[1 + g] * rs;
    }
  }
#undef STAGE_A
#undef LOADB
#undef READA
#undef DOMFMA
}

// softmax over f (196) per (b,l,g) row; one wave per row. scores pre-scaled.
__global__ void k_softmax(const float* __restrict__ scores, float* __restrict__ out) {
  const int wid = blockIdx.x * 4 + (threadIdx.x >> 6);
  const int lane = threadIdx.x & 63;
  const int b = wid / (kNL * kNG);
  const int rem = wid % (kNL * kNG);
  const int l = rem / kNG, g = rem % kNG;
  float sv[4];
  float mx = -1e30f;
#pragma unroll
  for (int u = 0; u < 4; ++u) {
    const int f = lane + 64 * u;
    if (f < kNF) {
      const size_t t = (size_t)b * kNTokL + (size_t)l * kNF + f;
      sv[u] = scores[(size_t)g * (kB * kNTokL) + t];
      mx = fmaxf(mx, sv[u]);
    } else {
      sv[u] = 0.f;
    }
  }
#pragma unroll
  for (int off = 32; off > 0; off >>= 1) mx = fmaxf(mx, __shfl_xor(mx, off));
  float se = 0.f;
#pragma unroll
  for (int u = 0; u < 4; ++u) {
    const int f = lane + 64 * u;
    const float e = (f < kNF) ? expf(sv[u] - mx) : 0.f;
    sv[u] = e;
    se += e;
  }
#pragma unroll
  for (int off = 32; off > 0; off >>= 1) se += __shfl_xor(se, off);
  const float inv = 1.0f / se;
#pragma unroll
  for (int u = 0; u < 4; ++u) {
    const int f = lane + 64 * u;
    if (f < kNF) out[((size_t)(b * kNL + l) * kNG + g) * kNF + f] = sv[u] * inv;
  }
}

// ===================== launcher =====================

extern "C" void kernel_launch(void* const* d_in, const int* in_sizes, int n_in,
                              void* d_out, int out_size, void* d_ws, size_t ws_size,
                              hipStream_t stream) {
  (void)in_sizes; (void)n_in; (void)out_size; (void)ws_size;
  const float* gf = (const float*)d_in[0];  // [8,5,640]
  const float* lf = (const float*)d_in[1];  // [8,75,196,640]
  const float* Wq = (const float*)d_in[2];  // [640,640]
  const float* Wk = (const float*)d_in[3];  // [640,640]
  float* ws = (float*)d_ws;
  float* out = (float*)d_out;

  // workspace (float offsets): total ~4.2 MB
  float* s_l    = ws;            // 5120
  float* m      = ws + 5120;     // 5120
  float* gc     = ws + 10240;    // 25600
  float* gn     = ws + 35840;    // 25600
  float* scores = ws + 61440;    // 5*117600 = 588000  (layout [g][t])
  ushort* Wh    = (ushort*)(ws + 649440);  // 409600 shorts
  ushort* Wl    = (ushort*)(ws + 854240);  // 409600 shorts

  hipMemsetAsync(s_l, 0, (size_t)5120 * 4, stream);

  k_sum_local<<<dim3(kB, 64), 320, 0, stream>>>(lf, s_l);
  k_cvtW<<<200, 256, 0, stream>>>(Wk, Wh, Wl);
  k_proj_mean<<<(kB * kC) / 4, 256, 0, stream>>>(Wq, Wk, gf, s_l, m, gc);
  k_norm_g<<<kB * kNG, 256, 0, stream>>>(gc, gn);
  k_big<<<kTiles * kB, 512, 0, stream>>>(lf, Wh, Wl, m, gn, scores);
  k_softmax<<<750, 256, 0, stream>>>(scores, out);
}